// Round 1
// baseline (666.501 us; speedup 1.0000x reference)
//
#include <hip/hip_runtime.h>
#include <math.h>

// Problem constants (match reference)
#define NN 20000
#define EE 640000
// H=8 heads, DK=16, fused feature width 128 = H*DK = CV*DV

__global__ __launch_bounds__(128)
void attn_se3_kernel(const float* __restrict__ key,     // (E, 8, 16) flat
                     const float* __restrict__ q0,      // (N, 32, 1)
                     const float* __restrict__ q1,      // (N, 32, 3)
                     const float* __restrict__ val,     // (E, 32, 4) flat
                     const int*   __restrict__ dst,     // (E,) sorted
                     float*       __restrict__ out)     // [N*32 | N*96]
{
    const int n = blockIdx.x;        // node
    const int t = threadIdx.x;       // flat feature slot 0..127
    const int c  = t >> 2;           // channel 0..31
    const int dv = t & 3;            // degree slot 0..3

    // Load this thread's q element: fused (c,dv) -> query_0 if dv==0 else query_1
    float q;
    if (dv == 0) q = q0[n * 32 + c];
    else         q = q1[n * 96 + c * 3 + (dv - 1)];

    // Binary search edge range [start, end) for node n (dst is sorted)
    int lo = 0, hi = EE;
    while (lo < hi) { int mid = (lo + hi) >> 1; if (dst[mid] <  n) lo = mid + 1; else hi = mid; }
    const int start = lo;
    hi = EE;
    while (lo < hi) { int mid = (lo + hi) >> 1; if (dst[mid] <= n) lo = mid + 1; else hi = mid; }
    const int end = lo;

    float r = 0.0f;
    if (start < end) {
        const float scale = 0.08838834764831845f;  // 1/sqrt(128)
        float m = -INFINITY, l = 0.0f, acc = 0.0f;

        // register prefetch of first edge
        float kc = key[(long)start * 128 + t];
        float vc = val[(long)start * 128 + t];

        for (int e = start; e < end; ++e) {
            float kn = 0.0f, vn = 0.0f;
            if (e + 1 < end) {   // issue next edge's loads before this edge's exp chain
                kn = key[(long)(e + 1) * 128 + t];
                vn = val[(long)(e + 1) * 128 + t];
            }
            // per-head dot: reduce over the 16 lanes of this head (t>>4)
            float p = kc * q;
            p += __shfl_xor(p, 1);
            p += __shfl_xor(p, 2);
            p += __shfl_xor(p, 4);
            p += __shfl_xor(p, 8);
            const float s  = p * scale;
            const float nm = fmaxf(m, s);
            const float alpha = __expf(m - nm);   // exp(-inf)=0 on first iter
            const float w     = __expf(s - nm);
            l   = l   * alpha + w;
            acc = acc * alpha + w * vc;
            m = nm;
            kc = kn; vc = vn;
        }
        r = acc / l;
    }
    // every output element must be written (d_out is poisoned before each run)
    if (dv == 0) out[n * 32 + c] = r;
    else         out[NN * 32 + n * 96 + c * 3 + (dv - 1)] = r;
}

extern "C" void kernel_launch(void* const* d_in, const int* in_sizes, int n_in,
                              void* d_out, int out_size, void* d_ws, size_t ws_size,
                              hipStream_t stream) {
    const float* key = (const float*)d_in[0];
    const float* q0  = (const float*)d_in[1];
    const float* q1  = (const float*)d_in[2];
    const float* val = (const float*)d_in[3];
    const int*   dst = (const int*)d_in[4];
    float* out = (float*)d_out;

    attn_se3_kernel<<<NN, 128, 0, stream>>>(key, q0, q1, val, dst, out);
}

// Round 2
// 631.745 us; speedup vs baseline: 1.0550x; 1.0550x over previous
//
#include <hip/hip_runtime.h>
#include <math.h>

#define NN 20000
#define EE 640000

// Build CSR row offsets from sorted dst: offs[n] = first edge with dst >= n.
// offs has NN+1 entries; every entry is written every call (ws is poisoned).
__global__ __launch_bounds__(256)
void build_offsets(const int* __restrict__ dst, int* __restrict__ offs) {
    int e = blockIdx.x * 256 + threadIdx.x;
    if (e >= EE) return;
    int d = dst[e];
    if (e == 0) {
        for (int j = 0; j <= d; ++j) offs[j] = 0;
    } else {
        int dp = dst[e - 1];
        for (int j = dp + 1; j <= d; ++j) offs[j] = e;
    }
    if (e == EE - 1) {
        for (int j = d + 1; j <= NN; ++j) offs[j] = EE;
    }
}

// One wave per node. Lane layout: s = lane>>5 (edge slot 0/1), cl = lane&31.
// Lane covers feature quad f = 4*cl .. 4*cl+3 of its slot's edge as float4.
// Head h = f>>4 = cl>>2  -> head dot reduces over the 4-lane group (xor 1,2).
// Online softmax per slot; slots merged via shfl_xor 32 at the end.
__global__ __launch_bounds__(256)
void attn_se3_kernel(const float* __restrict__ key,   // (E,128)
                     const float* __restrict__ q0,    // (N,32)
                     const float* __restrict__ q1,    // (N,96)
                     const float* __restrict__ val,   // (E,128)
                     const int*   __restrict__ offs,  // (N+1,)
                     float*       __restrict__ out)   // [N*32 | N*96]
{
    const int wid  = threadIdx.x >> 6;
    const int lane = threadIdx.x & 63;
    const int n    = blockIdx.x * 4 + wid;
    const int s    = lane >> 5;
    const int cl   = lane & 31;

    // q for features 4cl..4cl+3
    float4 qv;
    qv.x = q0[n * 32 + cl];
    qv.y = q1[n * 96 + cl * 3 + 0];
    qv.z = q1[n * 96 + cl * 3 + 1];
    qv.w = q1[n * 96 + cl * 3 + 2];

    const int start = offs[n];
    const int end   = offs[n + 1];
    const int deg   = end - start;
    const int iters = (deg + 1) >> 1;

    const float scale = 0.08838834764831845f;  // 1/sqrt(128)
    float m = -1e30f, l = 0.0f;
    float4 acc = make_float4(0.f, 0.f, 0.f, 0.f);

    int e = start + s;
    float4 kc = make_float4(0.f, 0.f, 0.f, 0.f);
    float4 vc = kc;
    if (e < end) {
        kc = *(const float4*)(key + (long)e * 128 + cl * 4);
        vc = *(const float4*)(val + (long)e * 128 + cl * 4);
    }

    for (int i = 0; i < iters; ++i) {
        const int en = e + 2;
        float4 kn = make_float4(0.f, 0.f, 0.f, 0.f);
        float4 vn = kn;
        if (en < end) {   // prefetch next pair before this iteration's chain
            kn = *(const float4*)(key + (long)en * 128 + cl * 4);
            vn = *(const float4*)(val + (long)en * 128 + cl * 4);
        }
        const bool valid = (e < end);
        float p = fmaf(kc.x, qv.x, fmaf(kc.y, qv.y, fmaf(kc.z, qv.z, kc.w * qv.w)));
        p += __shfl_xor(p, 1);
        p += __shfl_xor(p, 2);
        const float sc = valid ? p * scale : -1e30f;
        const float nm = fmaxf(m, sc);
        const float al = __expf(m - nm);           // exp(very-negative) -> 0
        const float w  = valid ? __expf(sc - nm) : 0.0f;
        l = l * al + w;
        acc.x = fmaf(w, vc.x, acc.x * al);
        acc.y = fmaf(w, vc.y, acc.y * al);
        acc.z = fmaf(w, vc.z, acc.z * al);
        acc.w = fmaf(w, vc.w, acc.w * al);
        m = nm;
        kc = kn; vc = vn; e = en;
    }

    // merge the two slots (lane ^ 32)
    const float m2 = __shfl_xor(m, 32);
    const float l2 = __shfl_xor(l, 32);
    float4 a2;
    a2.x = __shfl_xor(acc.x, 32);
    a2.y = __shfl_xor(acc.y, 32);
    a2.z = __shfl_xor(acc.z, 32);
    a2.w = __shfl_xor(acc.w, 32);
    const float mm = fmaxf(m, m2);
    const float b1 = __expf(m - mm);
    const float b2 = __expf(m2 - mm);
    const float ll = l * b1 + l2 * b2;

    if (lane < 32) {
        const float inv = (ll > 0.f) ? 1.0f / ll : 0.0f;  // deg==0 -> zeros
        const float rx = fmaf(acc.x, b1, a2.x * b2) * inv;
        const float ry = fmaf(acc.y, b1, a2.y * b2) * inv;
        const float rz = fmaf(acc.z, b1, a2.z * b2) * inv;
        const float rw = fmaf(acc.w, b1, a2.w * b2) * inv;
        out[n * 32 + cl] = rx;                    // dv == 0
        float* o1 = out + NN * 32 + n * 96 + cl * 3;
        o1[0] = ry; o1[1] = rz; o1[2] = rw;       // dv == 1..3
    }
}

extern "C" void kernel_launch(void* const* d_in, const int* in_sizes, int n_in,
                              void* d_out, int out_size, void* d_ws, size_t ws_size,
                              hipStream_t stream) {
    const float* key = (const float*)d_in[0];
    const float* q0  = (const float*)d_in[1];
    const float* q1  = (const float*)d_in[2];
    const float* val = (const float*)d_in[3];
    const int*   dst = (const int*)d_in[4];
    float* out = (float*)d_out;
    int*   offs = (int*)d_ws;   // needs (NN+1)*4 = 80004 bytes

    build_offsets<<<(EE + 255) / 256, 256, 0, stream>>>(dst, offs);
    attn_se3_kernel<<<NN / 4, 256, 0, stream>>>(key, q0, q1, val, offs, out);
}